// Round 10
// baseline (419.081 us; speedup 1.0000x reference)
//
#include <hip/hip_runtime.h>
#include <hip/hip_bf16.h>

#define CC 192

typedef __attribute__((ext_vector_type(8))) short bf16x8;
typedef __attribute__((ext_vector_type(4))) float f32x4;

__device__ __forceinline__ unsigned short f2bf(float f) {
    unsigned int u = __float_as_uint(f);
    u = (u + 0x7fffu + ((u >> 16) & 1u)) >> 16;
    return (unsigned short)u;
}

__device__ __forceinline__ f32x4 mfma16(bf16x8 a, bf16x8 b, f32x4 c) {
    return __builtin_amdgcn_mfma_f32_16x16x32_bf16(a, b, c, 0, 0, 0);
}

// Merged prep: 4 weight transposes (f32 [K][N] -> bf16 [N][K]) + bias expand.
__global__ void k_prep(const float* __restrict__ qkv_w, const float* __restrict__ proj_w,
                       const float* __restrict__ w1, const float* __restrict__ w2,
                       const float* __restrict__ relTab,
                       unsigned short* __restrict__ qkvT, unsigned short* __restrict__ projT,
                       unsigned short* __restrict__ w1T, unsigned short* __restrict__ w2T,
                       float* __restrict__ biasT) {
    int idx = blockIdx.x * blockDim.x + threadIdx.x;
    if (idx < 110592) { int n = idx / 192, k = idx % 192; qkvT[idx] = f2bf(qkv_w[k * 576 + n]); return; }
    idx -= 110592;
    if (idx < 36864)  { int n = idx / 192, k = idx % 192; projT[idx] = f2bf(proj_w[k * 192 + n]); return; }
    idx -= 36864;
    if (idx < 73728)  { int n = idx / 192, k = idx % 192; w1T[idx] = f2bf(w1[k * 384 + n]); return; }
    idx -= 73728;
    if (idx < 73728)  { int n = idx / 384, k = idx % 384; w2T[idx] = f2bf(w2[k * 192 + n]); return; }
    idx -= 73728;
    if (idx < 24576) {
        int h = idx >> 12, i = (idx >> 6) & 63, j = idx & 63;
        int yi = i >> 3, xi = i & 7, yj = j >> 3, xj = j & 7;
        int rel = (yi - yj + 7) * 15 + (xi - xj + 7);
        biasT[idx] = relTab[rel * 6 + h];
    }
}

// FUSED Swin block, 60.25 KB LDS (target: 2 blocks/CU), 12 waves (768 threads).
// Static LDS map (byte offsets into smem[61440], lifetimes time-shared):
//   A   [0,24576)      LN1 out, swz [64][192]; dies at bar2
//   VT  [0,12288)      V^T HALF [6 head][32 d][32 k] (2 KB/head); half0 then half1
//   Q   [12288,36864)  [6][64][32] swz; dies after qf loads (bar4)
//   K   [36864,61440)  [6][64][32] swz; dies after kf loads (bar4)
//   P   [12288,61440)  [6][64][64] swz (8 KB/head), overlays Q+K after bar4
//   AO/A2 [0,24576)    attn-out then LN2-out, swz [64][192]
//   G   [24576,49152)  MLP hidden HALF [64][192] swz, two passes
__global__ __launch_bounds__(768, 6) void k_fused(
    const float* __restrict__ x,
    const float* __restrict__ n1g, const float* __restrict__ n1b,
    const unsigned short* __restrict__ qkvT, const float* __restrict__ qkv_b,
    const unsigned short* __restrict__ projT, const float* __restrict__ proj_b,
    const float* __restrict__ biasTab,
    const float* __restrict__ n2g, const float* __restrict__ n2b,
    const unsigned short* __restrict__ w1T, const float* __restrict__ b1,
    const unsigned short* __restrict__ w2T, const float* __restrict__ b2,
    float* __restrict__ out)
{
    __shared__ __align__(16) char smem[61440];
    __shared__ int sOpos[64];

    const int tid = threadIdx.x;
    const int wid = blockIdx.x;
    const int b = wid >> 6;
    const int win = wid & 63;
    const int wh = win >> 3, ww = win & 7;
    const int lane = tid & 63;
    const int wave = tid >> 6;
    const int lhi = lane >> 4, llo = lane & 15;

    // ---------- Phase 1: LN1 + shifted window gather (512 threads, 8/token) ----------
    if (tid < 512) {
        const int tok = tid >> 3;
        const int ch0 = (tid & 7) * 24;
        const int yi = tok >> 3, xi = tok & 7;
        const int oy = (wh * 8 + yi + 4) & 63;
        const int ox = (ww * 8 + xi + 4) & 63;
        const int base = ((b * 64 + oy) * 64 + ox) * CC;
        if ((tid & 7) == 0) sOpos[tok] = base;
        float v[24];
        float s = 0.f, ss = 0.f;
        #pragma unroll
        for (int i = 0; i < 6; ++i) {
            const float4 f = *(const float4*)(x + base + ch0 + i * 4);
            v[i*4+0]=f.x; v[i*4+1]=f.y; v[i*4+2]=f.z; v[i*4+3]=f.w;
            s  += f.x + f.y + f.z + f.w;
            ss += f.x*f.x + f.y*f.y + f.z*f.z + f.w*f.w;
        }
        s  += __shfl_xor(s, 1);  s  += __shfl_xor(s, 2);  s  += __shfl_xor(s, 4);
        ss += __shfl_xor(ss, 1); ss += __shfl_xor(ss, 2); ss += __shfl_xor(ss, 4);
        const float mean = s * (1.f / 192.f);
        const float rstd = rsqrtf(ss * (1.f / 192.f) - mean * mean + 1e-5f);
        char* aBase = smem + tok * 384;
        const int sw = (tok & 7) << 4;
        #pragma unroll
        for (int i = 0; i < 12; ++i) {
            const int c = ch0 + i * 2;
            const float a0 = (v[i*2+0] - mean) * rstd * n1g[c]   + n1b[c];
            const float a1 = (v[i*2+1] - mean) * rstd * n1g[c+1] + n1b[c+1];
            *(unsigned int*)(aBase + ((c * 2) ^ sw)) =
                (unsigned int)f2bf(a0) | ((unsigned int)f2bf(a1) << 16);
        }
    }
    __syncthreads();   // bar1: A ready

    // ---------- Phase 2: QKV GEMM. wave w: Q|K cols [32w,+32), V cols [384+16w,+16) ----------
    const int w = wave;
    f32x4 accQK[4][2] = {};
    f32x4 accV[4] = {};
    {
        const int cb = 32 * w;
        const int cv = 384 + 16 * w;
        #pragma unroll
        for (int ks = 0; ks < 6; ++ks) {
            bf16x8 af[4];
            const int kbyte = ks * 64 + lhi * 16;
            #pragma unroll
            for (int m = 0; m < 4; ++m) {
                const int row = m * 16 + llo;
                af[m] = *(const bf16x8*)(smem + row * 384 + (kbyte ^ ((row & 7) << 4)));
            }
            #pragma unroll
            for (int n = 0; n < 2; ++n) {
                const bf16x8 bfr = *(const bf16x8*)(qkvT + (cb + n * 16 + llo) * 192 + ks * 32 + lhi * 8);
                #pragma unroll
                for (int m = 0; m < 4; ++m) accQK[m][n] = mfma16(af[m], bfr, accQK[m][n]);
            }
            const bf16x8 bfv = *(const bf16x8*)(qkvT + (cv + llo) * 192 + ks * 32 + lhi * 8);
            #pragma unroll
            for (int m = 0; m < 4; ++m) accV[m] = mfma16(af[m], bfv, accV[m]);
        }
    }
    __syncthreads();   // bar2: A dead everywhere

    // ---------- Phase 3: scatter Q|K (+bias, SCALE on Q) and VT-half0 ----------
    {
        const bool isK = (w >= 6);
        char* const dst = smem + (isK ? 36864 + (w - 6) * 4096 : 12288 + w * 4096);
        #pragma unroll
        for (int n = 0; n < 2; ++n) {
            const int d = n * 16 + llo;
            const float bia = qkv_b[32 * w + n * 16 + llo];
            #pragma unroll
            for (int m = 0; m < 4; ++m) {
                #pragma unroll
                for (int r = 0; r < 4; ++r) {
                    const int row = m * 16 + lhi * 4 + r;
                    float vv = accQK[m][n][r] + bia;
                    if (!isK) vv *= 0.17677669529663687f;
                    *(unsigned short*)(dst + row * 64 + ((2 * d) ^ ((row & 3) << 4))) = f2bf(vv);
                }
            }
        }
        // VT-half0: V rows 0..31 (accV m=0,1)
        const float bv = qkv_b[384 + 16 * w + llo];
        const int dl = (w & 1) * 16 + llo;
        char* const vdst = smem + (w >> 1) * 2048;
        #pragma unroll
        for (int m = 0; m < 2; ++m) {
            #pragma unroll
            for (int r = 0; r < 4; ++r) {
                const int k = m * 16 + lhi * 4 + r;
                *(unsigned short*)(vdst + dl * 64 + ((2 * k) ^ ((dl & 3) << 4))) = f2bf(accV[m][r] + bv);
            }
        }
    }
    __syncthreads();   // bar3: Q/K/VT0 visible

    // ---------- Phase 4/5: attention (head = w>>1, row-half = w&1) ----------
    const int h = w >> 1;
    const int mh = w & 1;
    f32x4 pacc[2][2] = {};
    float rinv[2][4];
    {
        bf16x8 qf[2], kf[4];
        #pragma unroll
        for (int m = 0; m < 2; ++m) {
            const int t = (mh * 2 + m) * 16 + llo;
            qf[m] = *(const bf16x8*)(smem + 12288 + h * 4096 + t * 64 + ((lhi * 16) ^ ((t & 3) << 4)));
        }
        #pragma unroll
        for (int n = 0; n < 4; ++n) {
            const int t = n * 16 + llo;
            kf[n] = *(const bf16x8*)(smem + 36864 + h * 4096 + t * 64 + ((lhi * 16) ^ ((t & 3) << 4)));
        }
        __syncthreads();   // bar4: Q/K in regs everywhere; P region writable

        f32x4 sacc[2][4] = {};
        #pragma unroll
        for (int m = 0; m < 2; ++m)
            #pragma unroll
            for (int n = 0; n < 4; ++n)
                sacc[m][n] = mfma16(qf[m], kf[n], sacc[m][n]);

        const bool eH = (wh == 7), eW = (ww == 7);
        int idj[4];
        #pragma unroll
        for (int n = 0; n < 4; ++n) {
            const int j = n * 16 + llo;
            idj[n] = (eH ? ((j >> 3) >= 4 ? 2 : 1) : 0) * 3 + (eW ? ((j & 7) >= 4 ? 2 : 1) : 0);
        }
        const float* bT = biasTab + h * 4096;
        // no-max softmax; P stores unnormalized e (rinv applied at AO)
        #pragma unroll
        for (int m = 0; m < 2; ++m) {
            #pragma unroll
            for (int r = 0; r < 4; ++r) {
                const int i = (mh * 2 + m) * 16 + lhi * 4 + r;
                const int idi = (eH ? ((i >> 3) >= 4 ? 2 : 1) : 0) * 3 +
                                (eW ? ((i & 7) >= 4 ? 2 : 1) : 0);
                float sum = 0.f;
                unsigned short pb[4];
                #pragma unroll
                for (int n = 0; n < 4; ++n) {
                    const int j = n * 16 + llo;
                    float e = __expf(sacc[m][n][r] + bT[i * 64 + j]);
                    if (idi != idj[n]) e = 0.f;
                    sum += e;
                    pb[n] = f2bf(e);
                }
                sum += __shfl_xor(sum, 1);
                sum += __shfl_xor(sum, 2);
                sum += __shfl_xor(sum, 4);
                sum += __shfl_xor(sum, 8);
                rinv[m][r] = 1.f / sum;
                #pragma unroll
                for (int n = 0; n < 4; ++n) {
                    const int j = n * 16 + llo;
                    *(unsigned short*)(smem + 12288 + h * 8192 + i * 128 + ((2 * j) ^ ((i & 7) << 4))) = pb[n];
                }
            }
        }
        // PV pass0: P[:,0:32] x V[0:32,:] (P wave-private rows; VT0 shared -> reads pre-bar5)
        {
            bf16x8 pf[2];
            #pragma unroll
            for (int m = 0; m < 2; ++m) {
                const int t = (mh * 2 + m) * 16 + llo;
                pf[m] = *(const bf16x8*)(smem + 12288 + h * 8192 + t * 128 + ((lhi * 16) ^ ((t & 7) << 4)));
            }
            #pragma unroll
            for (int n = 0; n < 2; ++n) {
                const int d = n * 16 + llo;
                const bf16x8 vf = *(const bf16x8*)(smem + h * 2048 + d * 64 + ((lhi * 16) ^ ((d & 3) << 4)));
                #pragma unroll
                for (int m = 0; m < 2; ++m) pacc[m][n] = mfma16(pf[m], vf, pacc[m][n]);
            }
        }
    }
    __syncthreads();   // bar5: all pass0 VT reads done
    // VT-half1: V rows 32..63 (accV m=2,3) into same 12 KB
    {
        const float bv = qkv_b[384 + 16 * w + llo];
        const int dl = (w & 1) * 16 + llo;
        char* const vdst = smem + (w >> 1) * 2048;
        #pragma unroll
        for (int m = 0; m < 2; ++m) {
            #pragma unroll
            for (int r = 0; r < 4; ++r) {
                const int k = m * 16 + lhi * 4 + r;   // local k in [0,32) for rows 32..63
                *(unsigned short*)(vdst + dl * 64 + ((2 * k) ^ ((dl & 3) << 4))) = f2bf(accV[m + 2][r] + bv);
            }
        }
    }
    __syncthreads();   // bar6: VT1 visible
    // PV pass1: P[:,32:64] x V[32:64,:]
    {
        bf16x8 pf[2];
        #pragma unroll
        for (int m = 0; m < 2; ++m) {
            const int t = (mh * 2 + m) * 16 + llo;
            pf[m] = *(const bf16x8*)(smem + 12288 + h * 8192 + t * 128 + ((64 + lhi * 16) ^ ((t & 7) << 4)));
        }
        #pragma unroll
        for (int n = 0; n < 2; ++n) {
            const int d = n * 16 + llo;
            const bf16x8 vf = *(const bf16x8*)(smem + h * 2048 + d * 64 + ((lhi * 16) ^ ((d & 3) << 4)));
            #pragma unroll
            for (int m = 0; m < 2; ++m) pacc[m][n] = mfma16(pf[m], vf, pacc[m][n]);
        }
    }
    __syncthreads();   // bar7: VT/P dead; [0,24K) free for AO
    // AO -> [0,24K) swz [64][192]
    {
        #pragma unroll
        for (int m = 0; m < 2; ++m) {
            #pragma unroll
            for (int n = 0; n < 2; ++n) {
                const int c = h * 32 + n * 16 + llo;
                #pragma unroll
                for (int r = 0; r < 4; ++r) {
                    const int i = (mh * 2 + m) * 16 + lhi * 4 + r;
                    *(unsigned short*)(smem + i * 384 + ((c * 2) ^ ((i & 7) << 4)))
                        = f2bf(pacc[m][n][r] * rinv[m][r]);
                }
            }
        }
    }
    __syncthreads();   // bar8: AO ready

    // ---------- Phase 6: proj GEMM + residual -> h to out; wave -> cols [16w,+16) ----------
    {
        f32x4 acc[4] = {};
        #pragma unroll
        for (int ks = 0; ks < 6; ++ks) {
            bf16x8 af[4];
            const int kbyte = ks * 64 + lhi * 16;
            #pragma unroll
            for (int m = 0; m < 4; ++m) {
                const int row = m * 16 + llo;
                af[m] = *(const bf16x8*)(smem + row * 384 + (kbyte ^ ((row & 7) << 4)));
            }
            const bf16x8 bfr = *(const bf16x8*)(projT + (16 * w + llo) * 192 + ks * 32 + lhi * 8);
            #pragma unroll
            for (int m = 0; m < 4; ++m) acc[m] = mfma16(af[m], bfr, acc[m]);
        }
        const int c = 16 * w + llo;
        const float pb = proj_b[c];
        #pragma unroll
        for (int m = 0; m < 4; ++m) {
            #pragma unroll
            for (int r = 0; r < 4; ++r) {
                const int i = m * 16 + lhi * 4 + r;
                const int base = sOpos[i];
                out[base + c] = x[base + c] + acc[m][r] + pb;
            }
        }
    }
    __syncthreads();   // bar9: h written (vmcnt drained)

    // ---------- Phase 7: LN2 from out (L2-hot) -> A2 at [0,24K) ----------
    if (tid < 512) {
        const int tok = tid >> 3;
        const int ch0 = (tid & 7) * 24;
        const float* hp = out + sOpos[tok];
        float v[24]; float s = 0.f, ss = 0.f;
        #pragma unroll
        for (int i = 0; i < 6; ++i) {
            const float4 f = *(const float4*)(hp + ch0 + i * 4);
            v[i*4]=f.x; v[i*4+1]=f.y; v[i*4+2]=f.z; v[i*4+3]=f.w;
            s += f.x + f.y + f.z + f.w;
            ss += f.x*f.x + f.y*f.y + f.z*f.z + f.w*f.w;
        }
        s  += __shfl_xor(s, 1);  s  += __shfl_xor(s, 2);  s  += __shfl_xor(s, 4);
        ss += __shfl_xor(ss, 1); ss += __shfl_xor(ss, 2); ss += __shfl_xor(ss, 4);
        const float mean = s * (1.f / 192.f);
        const float rstd = rsqrtf(ss * (1.f / 192.f) - mean * mean + 1e-5f);
        char* aBase = smem + tok * 384;
        const int sw = (tok & 7) << 4;
        #pragma unroll
        for (int i = 0; i < 12; ++i) {
            const int c = ch0 + i * 2;
            const float a0 = (v[i*2]   - mean) * rstd * n2g[c]   + n2b[c];
            const float a1 = (v[i*2+1] - mean) * rstd * n2g[c+1] + n2b[c+1];
            *(unsigned int*)(aBase + ((c * 2) ^ sw)) =
                (unsigned int)f2bf(a0) | ((unsigned int)f2bf(a1) << 16);
        }
    }
    __syncthreads();   // bar10: A2 ready

    // ---------- Phase 8: MLP in two hidden halves, G-half buffer at [24K,48K) ----------
    f32x4 accM[4] = {};
    #pragma unroll
    for (int hh = 0; hh < 2; ++hh) {
        // GEMM1 half: out cols [hh*192 + 16w, +16), + exact GELU -> G
        {
            f32x4 a1[4] = {};
            #pragma unroll
            for (int ks = 0; ks < 6; ++ks) {
                bf16x8 af[4];
                const int kbyte = ks * 64 + lhi * 16;
                #pragma unroll
                for (int m = 0; m < 4; ++m) {
                    const int row = m * 16 + llo;
                    af[m] = *(const bf16x8*)(smem + row * 384 + (kbyte ^ ((row & 7) << 4)));
                }
                const bf16x8 bfr = *(const bf16x8*)(w1T + (hh * 192 + 16 * w + llo) * 192 + ks * 32 + lhi * 8);
                #pragma unroll
                for (int m = 0; m < 4; ++m) a1[m] = mfma16(af[m], bfr, a1[m]);
            }
            const int cl = 16 * w + llo;
            const float bb = b1[hh * 192 + cl];
            #pragma unroll
            for (int m = 0; m < 4; ++m) {
                #pragma unroll
                for (int r = 0; r < 4; ++r) {
                    const int i = m * 16 + lhi * 4 + r;
                    const float u = a1[m][r] + bb;
                    const float g = 0.5f * u * (1.f + erff(u * 0.70710678118654752f));
                    *(unsigned short*)(smem + 24576 + i * 384 + ((2 * cl) ^ ((i & 7) << 4))) = f2bf(g);
                }
            }
        }
        __syncthreads();   // G-half ready
        // GEMM2 partial: K = [hh*192, +192), wave -> out cols [16w,+16)
        {
            #pragma unroll
            for (int ks = 0; ks < 6; ++ks) {
                bf16x8 af[4];
                const int kbyte = ks * 64 + lhi * 16;
                #pragma unroll
                for (int m = 0; m < 4; ++m) {
                    const int row = m * 16 + llo;
                    af[m] = *(const bf16x8*)(smem + 24576 + row * 384 + (kbyte ^ ((row & 7) << 4)));
                }
                const bf16x8 bfr = *(const bf16x8*)(w2T + (16 * w + llo) * 384 + hh * 192 + ks * 32 + lhi * 8);
                #pragma unroll
                for (int m = 0; m < 4; ++m) accM[m] = mfma16(af[m], bfr, accM[m]);
            }
        }
        __syncthreads();   // G-half consumed (safe to overwrite)
    }
    // final residual writeout
    {
        const int c = 16 * w + llo;
        const float bb = b2[c];
        #pragma unroll
        for (int m = 0; m < 4; ++m) {
            #pragma unroll
            for (int r = 0; r < 4; ++r) {
                const int i = m * 16 + lhi * 4 + r;
                float* p = out + sOpos[i] + c;
                *p = *p + accM[m][r] + bb;
            }
        }
    }
}

extern "C" void kernel_launch(void* const* d_in, const int* in_sizes, int n_in,
                              void* d_out, int out_size, void* d_ws, size_t ws_size,
                              hipStream_t stream)
{
    const float* x      = (const float*)d_in[0];
    const float* n1g    = (const float*)d_in[1];
    const float* n1b    = (const float*)d_in[2];
    const float* qkv_w  = (const float*)d_in[3];
    const float* qkv_b  = (const float*)d_in[4];
    const float* proj_w = (const float*)d_in[5];
    const float* proj_b = (const float*)d_in[6];
    const float* relTab = (const float*)d_in[7];
    const float* n2g    = (const float*)d_in[8];
    const float* n2b    = (const float*)d_in[9];
    const float* w1     = (const float*)d_in[10];
    const float* b1     = (const float*)d_in[11];
    const float* w2     = (const float*)d_in[12];
    const float* b2     = (const float*)d_in[13];
    float* out = (float*)d_out;

    char* ws = (char*)d_ws;
    unsigned short* qkvT  = (unsigned short*)(ws);            // [576][192] bf16
    unsigned short* projT = (unsigned short*)(ws + 221184);   // [192][192] bf16
    unsigned short* w1T   = (unsigned short*)(ws + 294912);   // [384][192] bf16
    unsigned short* w2T   = (unsigned short*)(ws + 442368);   // [192][384] bf16
    float*          biasT = (float*)(ws + 589824);            // [6][64][64] f32

    k_prep<<<1248, 256, 0, stream>>>(qkv_w, proj_w, w1, w2, relTab, qkvT, projT, w1T, w2T, biasT);
    k_fused<<<2048, 768, 0, stream>>>(x, n1g, n1b, qkvT, qkv_b, projT, proj_b, biasT,
                                      n2g, n2b, w1T, b1, w2T, b2, out);
}